// Round 10
// baseline (66.413 us; speedup 1.0000x reference)
//
#include <hip/hip_runtime.h>

#define IMG_H 256
#define IMG_W 256
#define ROWS 16
#define NIMG 128
#define NWAVES (NIMG * (IMG_H / ROWS) * 2)   // 4096: img x 16 strips x 2 col-halves

__device__ __forceinline__ float ssim1(float mu1, float mu2, float spp, float stt, float spt) {
    const float C1 = 1e-4f, C2 = 9e-4f;
    float mu1s = mu1 * mu1, mu2s = mu2 * mu2, mu12 = mu1 * mu2;
    float s1 = spp - mu1s, s2 = stt - mu2s, s12 = spt - mu12;
    float num = (2.f * mu12 + C1) * (2.f * s12 + C2);
    float den = (mu1s + mu2s + C1) * (s1 + s2 + C2);
    return num * __builtin_amdgcn_rcpf(den);
}

// H-first separable SSIM, LDS-row family, fully software-pipelined (R10).
// R8/R9 post-mortem: per-step serial chain (load -> write -> read -> compute)
// exposed ~500+ cyc/step. Now: step j issues global loads for row j+2,
// writes row j+1 (loaded last step), reads row j (written last step).
// Both the vmcnt and the LDS write->read dependency span a FULL step.
// 4 waves/block, private LDS quadrants, no barriers (same-wave DS is
// in-order; compiler inserts exact lgkmcnt waits).
template<int ATOMIC>
__global__ __launch_bounds__(256) void ssim_main(
    const float* __restrict__ pred,
    const float* __restrict__ targ,
    const float* __restrict__ window,
    float* __restrict__ wsum)
{
    __shared__ float2 sbuf[4][2][136];   // [wave][dbuf][col c at idx c-X0+4]

    const int lane = threadIdx.x & 63;
    const int wid  = threadIdx.x >> 6;
    const int gw   = blockIdx.x * 4 + wid;   // 0..4095
    const int n    = gw >> 5;                // image
    const int r    = gw & 31;
    const int r0   = (r >> 1) * ROWS;        // strip start row
    const int X0   = (r & 1) << 7;           // column half: 0 or 128

    // exact 1D gaussian from w2d row 3: g[j] = w[21+j] / sum
    float g[7];
    {
        float sum = 0.f;
#pragma unroll
        for (int j = 0; j < 7; ++j) { g[j] = window[21 + j]; sum += g[j]; }
        float inv = 1.f / sum;
#pragma unroll
        for (int j = 0; j < 7; ++j) g[j] *= inv;
    }

    const float* pimg = pred + (size_t)n * (IMG_H * IMG_W);
    const float* timg = targ + (size_t)n * (IMG_H * IMG_W);
    const int mo = X0 + 2 * lane;     // own column pair

    // halo duty for lanes 0..5: left cols X0-3..X0-1 (idx 1..3),
    // right cols X0+128..X0+130 (idx 132..134)
    int hidx = 0, hcol = 0;
    if (lane < 3)      { hidx = lane + 1;   hcol = X0 - 3 + lane;   }
    else if (lane < 6) { hidx = lane + 129; hcol = X0 + 125 + lane; }
    const bool hv = (lane < 6) && ((unsigned)hcol < (unsigned)IMG_W);

    // mod-7 register windows: 2 cols x 5 quantities x 7 slots (static idx)
    float Amu[7], Atu[7], App[7], Att[7], Apt[7];
    float Bmu[7], Btu[7], Bpp[7], Btt[7], Bpt[7];
    float acc = 0.f;

    float2 Pr, Tr, Hr;   // pipeline regs: global data of the NEXT row to stage
    float2 P2, T2, H2;

#define GLOAD(J, RP, RT, RH) { \
    const int j_ = (J); \
    RP = make_float2(0.f, 0.f); RT = RP; RH = RP; \
    if ((unsigned)j_ < (unsigned)IMG_H) { \
        RP = *(const float2*)(pimg + j_ * IMG_W + mo); \
        RT = *(const float2*)(timg + j_ * IMG_W + mo); \
        if (hv) { \
            RH.x = pimg[j_ * IMG_W + hcol]; \
            RH.y = timg[j_ * IMG_W + hcol]; \
        } \
    } }

#define SWRITE(BSEL, RP, RT, RH) { \
    float2* sb = sbuf[wid][BSEL]; \
    *(float4*)(sb + 2 * lane + 4) = make_float4((RP).x, (RT).x, (RP).y, (RT).y); \
    if (lane < 6) sb[hidx] = (RH); }

#define TAP(K, P, T) { \
    float wp = g[K] * (P), wt = g[K] * (T); \
    m_  = fmaf(g[K], (P), m_);  u_  = fmaf(g[K], (T), u_); \
    pp_ = fmaf(wp, (P), pp_);   tt_ = fmaf(wt, (T), tt_); \
    pt_ = fmaf(wp, (T), pt_); }

#define HC(SLOT, MU, TU, PP, TT, PT, p0,p1,p2,p3,p4,p5,p6, t0,t1,t2,t3,t4,t5,t6) { \
    float m_ = 0.f, u_ = 0.f, pp_ = 0.f, tt_ = 0.f, pt_ = 0.f; \
    TAP(0, p0, t0) TAP(1, p1, t1) TAP(2, p2, t2) TAP(3, p3, t3) \
    TAP(4, p4, t4) TAP(5, p5, t5) TAP(6, p6, t6) \
    MU[SLOT] = m_; TU[SLOT] = u_; PP[SLOT] = pp_; TT[SLOT] = tt_; PT[SLOT] = pt_; }

// read row-j neighborhood from buf BSEL (written one step earlier) + H-conv
#define RDHC(BSEL, SLOT) { \
    const float2* sb = sbuf[wid][BSEL]; \
    float4 q0 = *(const float4*)(sb + 2 * lane); \
    float4 q1 = *(const float4*)(sb + 2 * lane + 2); \
    float4 q2 = *(const float4*)(sb + 2 * lane + 4); \
    float4 q3 = *(const float4*)(sb + 2 * lane + 6); \
    float2 q4 = sb[2 * lane + 8]; \
    HC(SLOT, Amu, Atu, App, Att, Apt, \
       q0.z, q1.x, q1.z, q2.x, q2.z, q3.x, q3.z, \
       q0.w, q1.y, q1.w, q2.y, q2.w, q3.y, q3.w) \
    HC(SLOT, Bmu, Btu, Bpp, Btt, Bpt, \
       q1.x, q1.z, q2.x, q2.z, q3.x, q3.z, q4.x, \
       q1.y, q1.w, q2.y, q2.w, q3.y, q3.w, q4.y) }

#define VD(A_, U) ( fmaf(g[6], A_[((U)+6)%7], fmaf(g[5], A_[((U)+5)%7], \
    fmaf(g[4], A_[((U)+4)%7], fmaf(g[3], A_[((U)+3)%7], fmaf(g[2], A_[((U)+2)%7], \
    fmaf(g[1], A_[((U)+1)%7], g[0] * A_[(U)%7])))))) )

#define OUTR(U) { \
    { float m1 = VD(Amu,U), m2 = VD(Atu,U), pp = VD(App,U), tt = VD(Att,U), pt = VD(Apt,U); \
      acc += ssim1(m1, m2, pp, tt, pt); } \
    { float m1 = VD(Bmu,U), m2 = VD(Btu,U), pp = VD(Bpp,U), tt = VD(Btt,U), pt = VD(Bpt,U); \
      acc += ssim1(m1, m2, pp, tt, pt); } }

// step jj (row j = r0-3+jj). Invariants at entry:
//   buf[jj&1] holds row j (write issued last step)
//   Pr/Tr/Hr hold row j+1's global data (loaded last step)
// Body: issue loads j+2; read+HC row j; write row j+1; shift regs; output.
#define STEPX(SLOT, JOFF, JJ, HASOUT, U) { \
    GLOAD(r0 + (JOFF) + 2, P2, T2, H2); \
    RDHC((JJ) & 1, SLOT) \
    SWRITE(((JJ) + 1) & 1, Pr, Tr, Hr) \
    Pr = P2; Tr = T2; Hr = H2; \
    if (HASOUT) { OUTR(U) } }

    // pre-pipeline: stage row r0-3 into buf[0]; load row r0-2 into regs
    GLOAD(r0 - 3, Pr, Tr, Hr);
    SWRITE(0, Pr, Tr, Hr);
    GLOAD(r0 - 2, Pr, Tr, Hr);

    // 22 steps fully unrolled: rows r0-3 .. r0+18; slot = jj%7; out U=(jj-6)%7
    STEPX(0, -3,  0, 0, 0)
    STEPX(1, -2,  1, 0, 0)
    STEPX(2, -1,  2, 0, 0)
    STEPX(3,  0,  3, 0, 0)
    STEPX(4,  1,  4, 0, 0)
    STEPX(5,  2,  5, 0, 0)
    STEPX(6,  3,  6, 1, 0)
    STEPX(0,  4,  7, 1, 1)
    STEPX(1,  5,  8, 1, 2)
    STEPX(2,  6,  9, 1, 3)
    STEPX(3,  7, 10, 1, 4)
    STEPX(4,  8, 11, 1, 5)
    STEPX(5,  9, 12, 1, 6)
    STEPX(6, 10, 13, 1, 0)
    STEPX(0, 11, 14, 1, 1)
    STEPX(1, 12, 15, 1, 2)
    STEPX(2, 13, 16, 1, 3)
    STEPX(3, 14, 17, 1, 4)
    STEPX(4, 15, 18, 1, 5)
    STEPX(5, 16, 19, 1, 6)
    STEPX(6, 17, 20, 1, 0)
    STEPX(0, 18, 21, 1, 1)

#undef GLOAD
#undef SWRITE
#undef TAP
#undef HC
#undef RDHC
#undef VD
#undef OUTR
#undef STEPX

    // wave reduce, one write (or atomic) per wave
#pragma unroll
    for (int off = 32; off > 0; off >>= 1)
        acc += __shfl_xor(acc, off, 64);
    if (lane == 0) {
        if (ATOMIC) atomicAdd(&wsum[0], acc);
        else        wsum[gw] = acc;
    }
}

// deterministic f64 tree-reduce of the 4096 per-wave partials
__global__ __launch_bounds__(256) void ssim_final_arr(
    const float* __restrict__ ws, float* __restrict__ out)
{
    __shared__ double sred[4];
    double sm = 0.0;
#pragma unroll
    for (int k = 0; k < NWAVES / 256; ++k)
        sm += (double)ws[threadIdx.x + k * 256];
#pragma unroll
    for (int off = 32; off > 0; off >>= 1)
        sm += __shfl_down(sm, off, 64);
    const int lane = threadIdx.x & 63, wid = threadIdx.x >> 6;
    if (lane == 0) sred[wid] = sm;
    __syncthreads();
    if (threadIdx.x == 0) {
        double tot = sred[0] + sred[1] + sred[2] + sred[3];
        out[0] = (float)(1.0 - tot * (1.0 / (128.0 * 256.0 * 256.0)));
    }
}

__global__ void ssim_final_sc(const float* __restrict__ ws, float* __restrict__ out)
{
    out[0] = 1.0f - ws[0] * (1.0f / (128.0f * 256.0f * 256.0f));
}

extern "C" void kernel_launch(void* const* d_in, const int* in_sizes, int n_in,
                              void* d_out, int out_size, void* d_ws, size_t ws_size,
                              hipStream_t stream)
{
    const float* pred   = (const float*)d_in[0];
    const float* targ   = (const float*)d_in[1];
    const float* window = (const float*)d_in[2];
    float* out = (float*)d_out;
    float* ws  = (float*)d_ws;

    if (ws_size >= NWAVES * sizeof(float)) {
        // every ws slot is written by the grid each call: no memset needed
        ssim_main<0><<<NWAVES / 4, 256, 0, stream>>>(pred, targ, window, ws);
        ssim_final_arr<<<1, 256, 0, stream>>>(ws, out);
    } else {
        hipMemsetAsync(ws, 0, sizeof(float), stream);
        ssim_main<1><<<NWAVES / 4, 256, 0, stream>>>(pred, targ, window, ws);
        ssim_final_sc<<<1, 1, 0, stream>>>(ws, out);
    }
    (void)in_sizes; (void)n_in; (void)out_size;
}

// Round 11
// 45.001 us; speedup vs baseline: 1.4758x; 1.4758x over previous
//
#include <hip/hip_runtime.h>

#define IMG_H 256
#define IMG_W 256
#define ROWS 16
#define NIMG 128
#define NWAVES (NIMG * (IMG_H / ROWS) * 2)   // 4096: img x 16 strips x 2 col-halves

__device__ __forceinline__ float ssim1(float mu1, float mu2, float spp, float stt, float spt) {
    const float C1 = 1e-4f, C2 = 9e-4f;
    float mu1s = mu1 * mu1, mu2s = mu2 * mu2, mu12 = mu1 * mu2;
    float s1 = spp - mu1s, s2 = stt - mu2s, s12 = spt - mu12;
    float num = (2.f * mu12 + C1) * (2.f * s12 + C2);
    float den = (mu1s + mu2s + C1) * (s1 + s2 + C2);
    return num * __builtin_amdgcn_rcpf(den);
}

// H-first separable SSIM, LDS-row family (R11 = R9 + one-step GLOBAL
// prefetch only). R10's write-behind pipeline needed 2 register
// generations -> 188 VGPR -> 2 waves/SIMD (66us). Here only the global
// load is decoupled (one step ahead, 6 extra live regs); the LDS
// write->read stays back-to-back in a SINGLE buffer (same-wave DS ops
// are in-order, ~120cyc exposed, no barrier). The ~400-500cyc global
// latency is covered by the previous step's compute.
// 4 waves/block, private LDS quadrants, no barriers.
template<int ATOMIC>
__global__ __launch_bounds__(256) void ssim_main(
    const float* __restrict__ pred,
    const float* __restrict__ targ,
    const float* __restrict__ window,
    float* __restrict__ wsum)
{
    __shared__ float2 sbuf[4][136];   // [wave][col c at idx c-X0+4], single buffer

    const int lane = threadIdx.x & 63;
    const int wid  = threadIdx.x >> 6;
    const int gw   = blockIdx.x * 4 + wid;   // 0..4095
    const int n    = gw >> 5;                // image
    const int r    = gw & 31;
    const int r0   = (r >> 1) * ROWS;        // strip start row
    const int X0   = (r & 1) << 7;           // column half: 0 or 128

    // exact 1D gaussian from w2d row 3: g[j] = w[21+j] / sum
    float g[7];
    {
        float sum = 0.f;
#pragma unroll
        for (int j = 0; j < 7; ++j) { g[j] = window[21 + j]; sum += g[j]; }
        float inv = 1.f / sum;
#pragma unroll
        for (int j = 0; j < 7; ++j) g[j] *= inv;
    }

    const float* pimg = pred + (size_t)n * (IMG_H * IMG_W);
    const float* timg = targ + (size_t)n * (IMG_H * IMG_W);
    const int mo = X0 + 2 * lane;     // own column pair

    // halo duty for lanes 0..5: left cols X0-3..X0-1 (idx 1..3),
    // right cols X0+128..X0+130 (idx 132..134)
    int hidx = 0, hcol = 0;
    if (lane < 3)      { hidx = lane + 1;   hcol = X0 - 3 + lane;   }
    else if (lane < 6) { hidx = lane + 129; hcol = X0 + 125 + lane; }
    const bool hv = (lane < 6) && ((unsigned)hcol < (unsigned)IMG_W);

    // mod-7 register windows: 2 cols x 5 quantities x 7 slots (static idx)
    float Amu[7], Atu[7], App[7], Att[7], Apt[7];
    float Bmu[7], Btu[7], Bpp[7], Btt[7], Bpt[7];
    float acc = 0.f;

    float2 Pr, Tr, Hr;   // prefetch regs: global data of the next row to stage

#define GLOAD(J) { \
    const int j_ = (J); \
    Pr = make_float2(0.f, 0.f); Tr = Pr; Hr = Pr; \
    if ((unsigned)j_ < (unsigned)IMG_H) { \
        Pr = *(const float2*)(pimg + j_ * IMG_W + mo); \
        Tr = *(const float2*)(timg + j_ * IMG_W + mo); \
        if (hv) { \
            Hr.x = pimg[j_ * IMG_W + hcol]; \
            Hr.y = timg[j_ * IMG_W + hcol]; \
        } \
    } }

#define TAP(K, P, T) { \
    float wp = g[K] * (P), wt = g[K] * (T); \
    m_  = fmaf(g[K], (P), m_);  u_  = fmaf(g[K], (T), u_); \
    pp_ = fmaf(wp, (P), pp_);   tt_ = fmaf(wt, (T), tt_); \
    pt_ = fmaf(wp, (T), pt_); }

#define HC(SLOT, MU, TU, PP, TT, PT, p0,p1,p2,p3,p4,p5,p6, t0,t1,t2,t3,t4,t5,t6) { \
    float m_ = 0.f, u_ = 0.f, pp_ = 0.f, tt_ = 0.f, pt_ = 0.f; \
    TAP(0, p0, t0) TAP(1, p1, t1) TAP(2, p2, t2) TAP(3, p3, t3) \
    TAP(4, p4, t4) TAP(5, p5, t5) TAP(6, p6, t6) \
    MU[SLOT] = m_; TU[SLOT] = u_; PP[SLOT] = pp_; TT[SLOT] = tt_; PT[SLOT] = pt_; }

#define VD(A_, U) ( fmaf(g[6], A_[((U)+6)%7], fmaf(g[5], A_[((U)+5)%7], \
    fmaf(g[4], A_[((U)+4)%7], fmaf(g[3], A_[((U)+3)%7], fmaf(g[2], A_[((U)+2)%7], \
    fmaf(g[1], A_[((U)+1)%7], g[0] * A_[(U)%7])))))) )

#define OUTR(U) { \
    { float m1 = VD(Amu,U), m2 = VD(Atu,U), pp = VD(App,U), tt = VD(Att,U), pt = VD(Apt,U); \
      acc += ssim1(m1, m2, pp, tt, pt); } \
    { float m1 = VD(Bmu,U), m2 = VD(Btu,U), pp = VD(Bpp,U), tt = VD(Btt,U), pt = VD(Bpt,U); \
      acc += ssim1(m1, m2, pp, tt, pt); } }

// step for row j = r0+JOFF. Entry invariant: Pr/Tr/Hr hold row j's global
// data (loaded one step earlier). Body: stage row j to LDS; issue 9-col
// neighborhood reads; issue row j+1's global loads (covered by the HC/VD
// compute below); H-conv into window slot; optional output row.
#define STEPX(SLOT, JOFF, HASOUT, U, DOLOAD) { \
    { \
        float2* sw = sbuf[wid]; \
        *(float4*)(sw + 2 * lane + 4) = make_float4(Pr.x, Tr.x, Pr.y, Tr.y); \
        if (lane < 6) sw[hidx] = Hr; \
    } \
    const float2* sb = sbuf[wid]; \
    float4 q0 = *(const float4*)(sb + 2 * lane); \
    float4 q1 = *(const float4*)(sb + 2 * lane + 2); \
    float4 q2 = *(const float4*)(sb + 2 * lane + 4); \
    float4 q3 = *(const float4*)(sb + 2 * lane + 6); \
    float2 q4 = sb[2 * lane + 8]; \
    if (DOLOAD) { GLOAD(r0 + (JOFF) + 1); } \
    HC(SLOT, Amu, Atu, App, Att, Apt, \
       q0.z, q1.x, q1.z, q2.x, q2.z, q3.x, q3.z, \
       q0.w, q1.y, q1.w, q2.y, q2.w, q3.y, q3.w) \
    HC(SLOT, Bmu, Btu, Bpp, Btt, Bpt, \
       q1.x, q1.z, q2.x, q2.z, q3.x, q3.z, q4.x, \
       q1.y, q1.w, q2.y, q2.w, q3.y, q3.w, q4.y) \
    if (HASOUT) { OUTR(U) } }

    // prologue: prefetch first halo row
    GLOAD(r0 - 3);

    // rows r0-3 .. r0+2 -> slots 0..5 (no output yet)
    STEPX(0, -3, 0, 0, 1)
    STEPX(1, -2, 0, 0, 1)
    STEPX(2, -1, 0, 0, 1)
    STEPX(3,  0, 0, 0, 1)
    STEPX(4,  1, 0, 0, 1)
    STEPX(5,  2, 0, 0, 1)

    // 2 x 7 steady-state steps (slot pattern repeats mod 7); rolled loop
    // (R9-proven: keeps allocator at ~108 VGPR vs 188 when fully unrolled)
#pragma unroll 1
    for (int jb = 0; jb < 2; ++jb) {
        const int base = 3 + jb * 7;
        STEPX(6, base,     1, 0, 1)
        STEPX(0, base + 1, 1, 1, 1)
        STEPX(1, base + 2, 1, 2, 1)
        STEPX(2, base + 3, 1, 3, 1)
        STEPX(3, base + 4, 1, 4, 1)
        STEPX(4, base + 5, 1, 5, 1)
        STEPX(5, base + 6, 1, 6, 1)
    }
    // tail: rows r0+17, r0+18 -> output rows r0+14, r0+15
    STEPX(6, 17, 1, 0, 1)
    STEPX(0, 18, 1, 1, 0)

#undef GLOAD
#undef TAP
#undef HC
#undef VD
#undef OUTR
#undef STEPX

    // wave reduce, one write (or atomic) per wave
#pragma unroll
    for (int off = 32; off > 0; off >>= 1)
        acc += __shfl_xor(acc, off, 64);
    if (lane == 0) {
        if (ATOMIC) atomicAdd(&wsum[0], acc);
        else        wsum[gw] = acc;
    }
}

// deterministic f64 tree-reduce of the 4096 per-wave partials
__global__ __launch_bounds__(256) void ssim_final_arr(
    const float* __restrict__ ws, float* __restrict__ out)
{
    __shared__ double sred[4];
    double sm = 0.0;
#pragma unroll
    for (int k = 0; k < NWAVES / 256; ++k)
        sm += (double)ws[threadIdx.x + k * 256];
#pragma unroll
    for (int off = 32; off > 0; off >>= 1)
        sm += __shfl_down(sm, off, 64);
    const int lane = threadIdx.x & 63, wid = threadIdx.x >> 6;
    if (lane == 0) sred[wid] = sm;
    __syncthreads();
    if (threadIdx.x == 0) {
        double tot = sred[0] + sred[1] + sred[2] + sred[3];
        out[0] = (float)(1.0 - tot * (1.0 / (128.0 * 256.0 * 256.0)));
    }
}

__global__ void ssim_final_sc(const float* __restrict__ ws, float* __restrict__ out)
{
    out[0] = 1.0f - ws[0] * (1.0f / (128.0f * 256.0f * 256.0f));
}

extern "C" void kernel_launch(void* const* d_in, const int* in_sizes, int n_in,
                              void* d_out, int out_size, void* d_ws, size_t ws_size,
                              hipStream_t stream)
{
    const float* pred   = (const float*)d_in[0];
    const float* targ   = (const float*)d_in[1];
    const float* window = (const float*)d_in[2];
    float* out = (float*)d_out;
    float* ws  = (float*)d_ws;

    if (ws_size >= NWAVES * sizeof(float)) {
        // every ws slot is written by the grid each call: no memset needed
        ssim_main<0><<<NWAVES / 4, 256, 0, stream>>>(pred, targ, window, ws);
        ssim_final_arr<<<1, 256, 0, stream>>>(ws, out);
    } else {
        hipMemsetAsync(ws, 0, sizeof(float), stream);
        ssim_main<1><<<NWAVES / 4, 256, 0, stream>>>(pred, targ, window, ws);
        ssim_final_sc<<<1, 1, 0, stream>>>(ws, out);
    }
    (void)in_sizes; (void)n_in; (void)out_size;
}

// Round 12
// 44.638 us; speedup vs baseline: 1.4878x; 1.0081x over previous
//
#include <hip/hip_runtime.h>

#define IMG_H 256
#define IMG_W 256
#define ROWS 16
#define NIMG 128
#define NWAVES (NIMG * 64)   // 8192: img x 16 row-strips x 4 col-quarters

__device__ __forceinline__ float ssim1(float mu1, float mu2, float spp, float stt, float spt) {
    const float C1 = 1e-4f, C2 = 9e-4f;
    float mu1s = mu1 * mu1, mu2s = mu2 * mu2, mu12 = mu1 * mu2;
    float s1 = spp - mu1s, s2 = stt - mu2s, s12 = spt - mu12;
    float num = (2.f * mu12 + C1) * (2.f * s12 + C2);
    float den = (mu1s + mu2s + C1) * (s1 + s2 + C2);
    return num * __builtin_amdgcn_rcpf(den);
}

// H-first separable SSIM, LDS-row family, 1 COL PER THREAD (R12).
// R11 post-mortem: VGPR=120 capped residency at 4 waves/SIMD and the grid
// supplied only 4 blocks/CU -> occupancy 18%, VALU 42%. The per-thread
// register window is the pressure source (2 cols x 5 qty x 7 = 70 regs).
// At 1 col/thread the window is 35 regs (R1 measured 44 VGPR total for
// this shape) -> ~5-6 waves/SIMD; and 64-col quarters double the wave
// count to 8192 (8 blocks/CU supply). Same proven step structure:
// single-buffer LDS row (in-order same-wave DS, no barriers), one-step
// global prefetch, rolled x2 steady loop.
template<int ATOMIC>
__global__ __launch_bounds__(256) void ssim_main(
    const float* __restrict__ pred,
    const float* __restrict__ targ,
    const float* __restrict__ window,
    float* __restrict__ wsum)
{
    __shared__ float2 sbuf[4][72];    // [wave][col c at idx c-X0+4], 576B/wave

    const int lane = threadIdx.x & 63;
    const int wid  = threadIdx.x >> 6;
    const int gw   = blockIdx.x * 4 + wid;   // 0..8191
    const int n    = gw >> 6;                // image
    const int r    = gw & 63;
    const int r0   = (r >> 2) * ROWS;        // strip start row
    const int X0   = (r & 3) << 6;           // col quarter: 0/64/128/192

    // exact 1D gaussian from w2d row 3: g[j] = w[21+j] / sum
    float g[7];
    {
        float sum = 0.f;
#pragma unroll
        for (int j = 0; j < 7; ++j) { g[j] = window[21 + j]; sum += g[j]; }
        float inv = 1.f / sum;
#pragma unroll
        for (int j = 0; j < 7; ++j) g[j] *= inv;
    }

    const float* pimg = pred + (size_t)n * (IMG_H * IMG_W);
    const float* timg = targ + (size_t)n * (IMG_H * IMG_W);
    const int mo = X0 + lane;         // own column

    // halo duty, lanes 0..5: left cols X0-3..X0-1 (idx 1..3),
    // right cols X0+64..X0+66 (idx 68..70)
    int hidx = 0, hcol = 0;
    if (lane < 3)      { hidx = lane + 1;  hcol = X0 - 3 + lane;  }
    else if (lane < 6) { hidx = lane + 65; hcol = X0 + 61 + lane; }
    const bool hv = (lane < 6) && ((unsigned)hcol < (unsigned)IMG_W);

    // mod-7 register window: 1 col x 5 quantities x 7 slots (static idx)
    float Amu[7], Atu[7], App[7], Att[7], Apt[7];
    float acc = 0.f;

    float Pr, Tr;        // prefetch regs for own column
    float2 Hr;           // prefetch reg for halo col (p,t)

#define GLOAD(J) { \
    const int j_ = (J); \
    Pr = 0.f; Tr = 0.f; Hr = make_float2(0.f, 0.f); \
    if ((unsigned)j_ < (unsigned)IMG_H) { \
        Pr = pimg[j_ * IMG_W + mo]; \
        Tr = timg[j_ * IMG_W + mo]; \
        if (hv) { \
            Hr.x = pimg[j_ * IMG_W + hcol]; \
            Hr.y = timg[j_ * IMG_W + hcol]; \
        } \
    } }

#define TAP(K, P, T) { \
    float wp = g[K] * (P), wt = g[K] * (T); \
    m_  = fmaf(g[K], (P), m_);  u_  = fmaf(g[K], (T), u_); \
    pp_ = fmaf(wp, (P), pp_);   tt_ = fmaf(wt, (T), tt_); \
    pt_ = fmaf(wp, (T), pt_); }

#define VD(A_, U) ( fmaf(g[6], A_[((U)+6)%7], fmaf(g[5], A_[((U)+5)%7], \
    fmaf(g[4], A_[((U)+4)%7], fmaf(g[3], A_[((U)+3)%7], fmaf(g[2], A_[((U)+2)%7], \
    fmaf(g[1], A_[((U)+1)%7], g[0] * A_[(U)%7])))))) )

#define OUTR(U) { \
    float m1 = VD(Amu,U), m2 = VD(Atu,U), pp = VD(App,U), tt = VD(Att,U), pt = VD(Apt,U); \
    acc += ssim1(m1, m2, pp, tt, pt); }

// step for row j = r0+JOFF. Entry: Pr/Tr/Hr hold row j (loaded last step).
// stage row j -> read 7-col neighborhood -> prefetch row j+1 -> H-conv ->
// optional output row. Single buffer: same-wave DS is in-order.
#define STEPX(SLOT, JOFF, HASOUT, U, DOLOAD) { \
    { \
        float2* sw = sbuf[wid]; \
        sw[lane + 4] = make_float2(Pr, Tr); \
        if (lane < 6) sw[hidx] = Hr; \
    } \
    const float2* sb = sbuf[wid]; \
    float2 q0 = sb[lane + 1], q1 = sb[lane + 2], q2 = sb[lane + 3]; \
    float2 q3 = sb[lane + 4], q4 = sb[lane + 5], q5 = sb[lane + 6]; \
    float2 q6 = sb[lane + 7]; \
    if (DOLOAD) { GLOAD(r0 + (JOFF) + 1); } \
    { \
        float m_ = 0.f, u_ = 0.f, pp_ = 0.f, tt_ = 0.f, pt_ = 0.f; \
        TAP(0, q0.x, q0.y) TAP(1, q1.x, q1.y) TAP(2, q2.x, q2.y) \
        TAP(3, q3.x, q3.y) TAP(4, q4.x, q4.y) TAP(5, q5.x, q5.y) \
        TAP(6, q6.x, q6.y) \
        Amu[SLOT] = m_; Atu[SLOT] = u_; App[SLOT] = pp_; \
        Att[SLOT] = tt_; Apt[SLOT] = pt_; \
    } \
    if (HASOUT) { OUTR(U) } }

    // prologue: prefetch first halo row
    GLOAD(r0 - 3);

    // rows r0-3 .. r0+2 -> slots 0..5 (no output yet)
    STEPX(0, -3, 0, 0, 1)
    STEPX(1, -2, 0, 0, 1)
    STEPX(2, -1, 0, 0, 1)
    STEPX(3,  0, 0, 0, 1)
    STEPX(4,  1, 0, 0, 1)
    STEPX(5,  2, 0, 0, 1)

    // 2 x 7 steady-state steps (slot pattern repeats mod 7); rolled loop
    // keeps the allocator lean (R9/R11-proven)
#pragma unroll 1
    for (int jb = 0; jb < 2; ++jb) {
        const int base = 3 + jb * 7;
        STEPX(6, base,     1, 0, 1)
        STEPX(0, base + 1, 1, 1, 1)
        STEPX(1, base + 2, 1, 2, 1)
        STEPX(2, base + 3, 1, 3, 1)
        STEPX(3, base + 4, 1, 4, 1)
        STEPX(4, base + 5, 1, 5, 1)
        STEPX(5, base + 6, 1, 6, 1)
    }
    // tail: rows r0+17, r0+18 -> output rows r0+14, r0+15
    STEPX(6, 17, 1, 0, 1)
    STEPX(0, 18, 1, 1, 0)

#undef GLOAD
#undef TAP
#undef VD
#undef OUTR
#undef STEPX

    // wave reduce, one write (or atomic) per wave
#pragma unroll
    for (int off = 32; off > 0; off >>= 1)
        acc += __shfl_xor(acc, off, 64);
    if (lane == 0) {
        if (ATOMIC) atomicAdd(&wsum[0], acc);
        else        wsum[gw] = acc;
    }
}

// deterministic f64 tree-reduce of the 8192 per-wave partials
__global__ __launch_bounds__(256) void ssim_final_arr(
    const float* __restrict__ ws, float* __restrict__ out)
{
    __shared__ double sred[4];
    double sm = 0.0;
#pragma unroll
    for (int k = 0; k < NWAVES / 256; ++k)
        sm += (double)ws[threadIdx.x + k * 256];
#pragma unroll
    for (int off = 32; off > 0; off >>= 1)
        sm += __shfl_down(sm, off, 64);
    const int lane = threadIdx.x & 63, wid = threadIdx.x >> 6;
    if (lane == 0) sred[wid] = sm;
    __syncthreads();
    if (threadIdx.x == 0) {
        double tot = sred[0] + sred[1] + sred[2] + sred[3];
        out[0] = (float)(1.0 - tot * (1.0 / (128.0 * 256.0 * 256.0)));
    }
}

__global__ void ssim_final_sc(const float* __restrict__ ws, float* __restrict__ out)
{
    out[0] = 1.0f - ws[0] * (1.0f / (128.0f * 256.0f * 256.0f));
}

extern "C" void kernel_launch(void* const* d_in, const int* in_sizes, int n_in,
                              void* d_out, int out_size, void* d_ws, size_t ws_size,
                              hipStream_t stream)
{
    const float* pred   = (const float*)d_in[0];
    const float* targ   = (const float*)d_in[1];
    const float* window = (const float*)d_in[2];
    float* out = (float*)d_out;
    float* ws  = (float*)d_ws;

    if (ws_size >= NWAVES * sizeof(float)) {
        // every ws slot is written by the grid each call: no memset needed
        ssim_main<0><<<NWAVES / 4, 256, 0, stream>>>(pred, targ, window, ws);
        ssim_final_arr<<<1, 256, 0, stream>>>(ws, out);
    } else {
        hipMemsetAsync(ws, 0, sizeof(float), stream);
        ssim_main<1><<<NWAVES / 4, 256, 0, stream>>>(pred, targ, window, ws);
        ssim_final_sc<<<1, 1, 0, stream>>>(ws, out);
    }
    (void)in_sizes; (void)n_in; (void)out_size;
}